// Round 24
// baseline (920.279 us; speedup 1.0000x reference)
//
#include <hip/hip_runtime.h>
#include <cstdint>
#include <cstddef>

// ---------------------------------------------------------------------------
// DualAttention: B=1024, L=196, H=1024, A=512
// R24 = R23 + two trims:
//  1) T5 s_setprio(1) around the MFMA clusters in both k_dual paths (mixed
//     spatial/channel residency = wave role-diversity, setprio's prereq).
//  2) build_wt + build_wct + k_ph merged into one k_prep kernel (independent
//     work, tiny grids -> co-scheduled, 2 launch gaps saved).
//  - k_dual bodies / interleave: R23 verbatim.  - k_weighted: R15 verbatim.
// ---------------------------------------------------------------------------

#define DEVI __device__ __forceinline__

typedef __bf16 bf16;
typedef bf16 bf16x4 __attribute__((ext_vector_type(4)));
typedef bf16 bf16x8 __attribute__((ext_vector_type(8)));
typedef float f32x4 __attribute__((ext_vector_type(4)));
typedef unsigned int uint32;

static constexpr int Bb = 1024;
static constexpr int Ll = 196;
static constexpr int Hh = 1024;
static constexpr int BL = Bb * Ll;        // 200704

#define LGKM0     asm volatile("s_waitcnt lgkmcnt(0)" ::: "memory")
#define SBAR()    __builtin_amdgcn_s_barrier()
#define SCHED0()  __builtin_amdgcn_sched_barrier(0)

DEVI float fast_tanh(float x) {
  float e = __expf(2.f * x);
  return 1.f - 2.f * __builtin_amdgcn_rcpf(e + 1.f);
}

DEVI uint32 packbf2(float a, float b) {
  union { bf16 h; unsigned short u; } x, y;
  x.h = (bf16)a; y.h = (bf16)b;
  return (uint32)x.u | ((uint32)y.u << 16);
}

// ---------------- merged prologue: panel builds + p_h ----------------------
// blocks 0..255: build WtP; 256..311: build WctP; 312..567: p_h = h@W_h+b_h.
// Panels: [k0/32][a=0..511][64B]; 16B slot s holds k-octet (s ^ g(a)),
// g(a) = (a>>1)&3.
__global__ void k_prep(const float* __restrict__ W_att, const float* __restrict__ W_ch,
                       const float* __restrict__ h, const float* __restrict__ W_h,
                       const float* __restrict__ b_h, bf16* __restrict__ WtP,
                       bf16* __restrict__ WctP, float* __restrict__ p_h) {
  const int bx = blockIdx.x;
  const int tid = threadIdx.x;
  if (bx < 256) {
    int idx = bx * 256 + tid;                    // 65536
    int a = idx & 511;
    int ko = (idx >> 9) << 3;
    bf16x8 v;
#pragma unroll
    for (int j = 0; j < 8; ++j) v[j] = (bf16)W_att[(size_t)(ko + j) * 512 + a];
    int panel = ko >> 5;
    int slot = ((ko >> 3) & 3) ^ ((a >> 1) & 3);
    *reinterpret_cast<bf16x8*>((char*)WtP + (size_t)panel * 32768 + a * 64 + slot * 16) = v;
  } else if (bx < 312) {
    int idx = (bx - 256) * 256 + tid;            // 14336
    int a = idx & 511;
    int lo = (idx >> 9) << 3;
    bf16x8 v;
#pragma unroll
    for (int j = 0; j < 8; ++j)
      v[j] = (lo + j < Ll) ? (bf16)W_ch[(size_t)(lo + j) * 512 + a] : (bf16)0.f;
    int panel = lo >> 5;
    int slot = ((lo >> 3) & 3) ^ ((a >> 1) & 3);
    *reinterpret_cast<bf16x8*>((char*)WctP + (size_t)panel * 32768 + a * 64 + slot * 16) = v;
  } else {
    int pidx = bx - 312;                         // 0..255
    int a = (pidx & 1) * 256 + tid;
    int b0 = (pidx >> 1) * 8;
    float acc[8] = {0.f, 0.f, 0.f, 0.f, 0.f, 0.f, 0.f, 0.f};
    for (int k = 0; k < 1024; ++k) {
      float w = W_h[(size_t)k * 512 + a];
#pragma unroll
      for (int i = 0; i < 8; ++i) acc[i] += h[(size_t)(b0 + i) * 1024 + k] * w;
    }
#pragma unroll
    for (int i = 0; i < 8; ++i) p_h[(size_t)(b0 + i) * 512 + a] = acc[i] + b_h[a];
  }
}

// ------------- fused GEMM kernel: spatial + channel co-scheduled -----------
// Grid = 64 groups x 177 blocks (49 spatial + 128 channel per group).
#define SP_ASTR 80
#define SP_ST   5120
#define CT_STR 464
#define CH_PHC 59392
#define CH_WB  61440
__launch_bounds__(512)
__global__ void k_dual(const float* __restrict__ att, const bf16* __restrict__ WtP,
                       const bf16* __restrict__ WctP, const float* __restrict__ b_att,
                       const float* __restrict__ b_ch, const float* __restrict__ p_h,
                       const float* __restrict__ w_alpha, const float* __restrict__ w_beta,
                       float* __restrict__ logits_s, float* __restrict__ logits_c) {
  __shared__ alignas(1024) char lds[63488];
  const int tid = threadIdx.x;
  const int lane = tid & 63;
  const int wn = tid >> 6;                  // 0..7
  const int l15 = lane & 15, l4 = lane >> 4;
  const int grpI = blockIdx.x / 177;        // 0..63
  const int rI = blockIdx.x % 177;

  if (rI < 49) {
    // ================== SPATIAL PATH ==================
    const int sb = grpI * 49 + rI;          // 0..3135
    const size_t row0 = (size_t)sb * 64;
    const int slotP = (l4 ^ ((l15 >> 1) & 3)) << 4;
    const int ar = tid >> 3;                // A rows 0..63
    const int aks = (tid & 7) << 2;         // k offset 0,4,...,28
    const char* WtPc = (const char*)WtP;
    const float* apbase = att + (row0 + ar) * 1024 + aks;
    const int awoff = ar * SP_ASTR + (aks << 1);
    int boff[4];
#pragma unroll
    for (int n = 0; n < 4; ++n) boff[n] = (wn * 64 + n * 16 + l15) * 64 + slotP;

    f32x4 acc[4][4];
#pragma unroll
    for (int m = 0; m < 4; ++m)
#pragma unroll
      for (int n = 0; n < 4; ++n) acc[m][n] = f32x4{0.f, 0.f, 0.f, 0.f};

    bf16x8 bvC0 = *reinterpret_cast<const bf16x8*>(WtPc + boff[0]);
    bf16x8 bvC1 = *reinterpret_cast<const bf16x8*>(WtPc + boff[1]);
    bf16x8 bvC2 = *reinterpret_cast<const bf16x8*>(WtPc + boff[2]);
    bf16x8 bvC3 = *reinterpret_cast<const bf16x8*>(WtPc + boff[3]);

#pragma unroll 1
    for (int ph = 0; ph < 4; ++ph) {
      {
        float4 c[8];
#pragma unroll
        for (int st = 0; st < 8; ++st)
          c[st] = *reinterpret_cast<const float4*>(apbase + ph * 256 + st * 32);
#pragma unroll
        for (int st = 0; st < 8; ++st) {
          bf16x4 w0 = {(bf16)c[st].x, (bf16)c[st].y, (bf16)c[st].z, (bf16)c[st].w};
          *reinterpret_cast<bf16x4*>(&lds[st * SP_ST + awoff]) = w0;
        }
      }
      LGKM0;
      SCHED0();
      SBAR();
      SCHED0();
#pragma unroll 1
      for (int st = 0; st < 8; ++st) {
        const int t = ph * 8 + st;
        bf16x8 bvN0 = bvC0, bvN1 = bvC1, bvN2 = bvC2, bvN3 = bvC3;
        if (t < 31) {
          const char* bpan = WtPc + (size_t)(t + 1) * 32768;
          bvN0 = *reinterpret_cast<const bf16x8*>(bpan + boff[0]);
          bvN1 = *reinterpret_cast<const bf16x8*>(bpan + boff[1]);
          bvN2 = *reinterpret_cast<const bf16x8*>(bpan + boff[2]);
          bvN3 = *reinterpret_cast<const bf16x8*>(bpan + boff[3]);
        }
        bf16x8 af[4];
#pragma unroll
        for (int m = 0; m < 4; ++m)
          af[m] = *reinterpret_cast<const bf16x8*>(
              &lds[st * SP_ST + (m * 16 + l15) * SP_ASTR + (l4 << 4)]);
        __builtin_amdgcn_s_setprio(1);       // T5: favor MFMA cluster
#pragma unroll
        for (int m = 0; m < 4; ++m) {
          acc[m][0] = __builtin_amdgcn_mfma_f32_16x16x32_bf16(af[m], bvC0, acc[m][0], 0, 0, 0);
          acc[m][1] = __builtin_amdgcn_mfma_f32_16x16x32_bf16(af[m], bvC1, acc[m][1], 0, 0, 0);
          acc[m][2] = __builtin_amdgcn_mfma_f32_16x16x32_bf16(af[m], bvC2, acc[m][2], 0, 0, 0);
          acc[m][3] = __builtin_amdgcn_mfma_f32_16x16x32_bf16(af[m], bvC3, acc[m][3], 0, 0, 0);
        }
        __builtin_amdgcn_s_setprio(0);
        bvC0 = bvN0; bvC1 = bvN1; bvC2 = bvN2; bvC3 = bvN3;
      }
      LGKM0;
      SCHED0();
      SBAR();
      SCHED0();
    }

    // epilogue
    float wa[4], ba[4], ph0[4], ph1[4];
    unsigned b0i = (unsigned)row0 / 196u;
    unsigned b1i = (unsigned)(row0 + 63) / 196u;
    unsigned bnd = (b0i + 1) * 196u;
#pragma unroll
    for (int n = 0; n < 4; ++n) {
      int a = wn * 64 + n * 16 + l15;
      wa[n] = w_alpha[a];
      ba[n] = b_att[a];
      ph0[n] = p_h[(size_t)b0i * 512 + a];
      ph1[n] = p_h[(size_t)b1i * 512 + a];
    }
    float* red = reinterpret_cast<float*>(lds);
#pragma unroll
    for (int m = 0; m < 4; ++m) {
#pragma unroll
      for (int j = 0; j < 4; ++j) {
        int rloc = m * 16 + l4 * 4 + j;
        unsigned R = (unsigned)row0 + rloc;
        bool hib = R >= bnd;
        float s = 0.f;
#pragma unroll
        for (int n = 0; n < 4; ++n)
          s += fast_tanh(acc[m][n][j] + ba[n] + (hib ? ph1[n] : ph0[n])) * wa[n];
        s += __shfl_xor(s, 1);
        s += __shfl_xor(s, 2);
        s += __shfl_xor(s, 4);
        s += __shfl_xor(s, 8);
        if (l15 == 0) red[wn * 64 + rloc] = s;
      }
    }
    __syncthreads();
    if (tid < 64) {
      float r = 0.f;
#pragma unroll
      for (int w = 0; w < 8; ++w) r += red[w * 64 + tid];
      logits_s[row0 + tid] = r;
    }
  } else {
    // ================== CHANNEL PATH ==================
    const int cidx = grpI * 128 + (rI - 49);  // 0..8191
    const int b = cidx >> 3;
    const int h0 = (cidx & 7) * 128;
    const float* attb = att + (size_t)b * Ll * 1024 + h0;
    const char* Pc = (const char*)WctP;
    const int slotP = (l4 ^ ((l15 >> 1) & 3)) << 4;
    const int slotT = (l4 ^ ((l15 >> 2) & 3)) << 4;
    int poff0 = (wn * 32 + l15) * 64 + slotP;
    int poff1 = (wn * 32 + 16 + l15) * 64 + slotP;

    float pr = p_h[(size_t)b * 512 + tid];
    float bc = b_ch[tid];
    float wb = w_beta[tid];
    bf16x8 avC0 = *reinterpret_cast<const bf16x8*>(Pc + poff0);
    bf16x8 avC1 = *reinterpret_cast<const bf16x8*>(Pc + poff1);
    {
      const int grp = tid >> 8;
      const int t2 = tid & 255;
      const int lp = t2 >> 4;
      const int hq = (t2 & 15) << 2;
      const int usw = lp ^ ((t2 & 3) << 2);
      const int ch0 = grp ? 4 : 0;
      const int nch = grp ? 3 : 4;
#pragma unroll
      for (int hh = 0; hh < 2; ++hh) {
        const int hb = hq + 64 * hh;
        float4 va[4], vb[4];
#pragma unroll
        for (int i = 0; i < 4; ++i) {
          if (i >= nch) break;
          int ch = ch0 + i;
          int lg = ch * 32 + 2 * lp;
          va[i] = float4{0.f, 0.f, 0.f, 0.f};
          vb[i] = float4{0.f, 0.f, 0.f, 0.f};
          if (lg < Ll)
            va[i] = *reinterpret_cast<const float4*>(&attb[(size_t)lg * 1024 + hb]);
          if (lg + 1 < Ll)
            vb[i] = *reinterpret_cast<const float4*>(&attb[(size_t)(lg + 1) * 1024 + hb]);
        }
#pragma unroll
        for (int i = 0; i < 4; ++i) {
          if (i >= nch) break;
          int ch = ch0 + i;
          uint32 pk[4] = {packbf2(va[i].x, vb[i].x), packbf2(va[i].y, vb[i].y),
                          packbf2(va[i].z, vb[i].z), packbf2(va[i].w, vb[i].w)};
#pragma unroll
          for (int c = 0; c < 4; ++c)
            *reinterpret_cast<uint32*>(
                &lds[(hb + c) * CT_STR + ch * 64 + 4 * usw]) = pk[c];
        }
      }
    }
    {
      float* phcL = reinterpret_cast<float*>(&lds[CH_PHC]);
      float* wbL = reinterpret_cast<float*>(&lds[CH_WB]);
      phcL[tid] = pr + bc;
      wbL[tid] = wb;
    }

    f32x4 acc[2][8];
#pragma unroll
    for (int m = 0; m < 2; ++m)
#pragma unroll
      for (int n = 0; n < 8; ++n) acc[m][n] = f32x4{0.f, 0.f, 0.f, 0.f};
    float sn[8] = {0.f, 0.f, 0.f, 0.f, 0.f, 0.f, 0.f, 0.f};
    const float* phcLc = reinterpret_cast<const float*>(&lds[CH_PHC]);
    const float* wbLc = reinterpret_cast<const float*>(&lds[CH_WB]);

    LGKM0;
    SCHED0();
    SBAR();
    SCHED0();

#pragma unroll 1
    for (int s = 0; s < 14; ++s) {
      const int tk = (s >= 7) ? s - 7 : s;
      bf16x8 avN0 = avC0, avN1 = avC1;
      if (s < 13) {
        const int s1 = s + 1;
        const char* pan = Pc + (size_t)((s1 >= 7) ? s1 - 7 : s1) * 32768 +
                          ((s1 >= 7) ? 16384 : 0);
        avN0 = *reinterpret_cast<const bf16x8*>(pan + poff0);
        avN1 = *reinterpret_cast<const bf16x8*>(pan + poff1);
      }
#pragma unroll
      for (int half = 0; half < 2; ++half) {
        bf16x8 bv[4];
#pragma unroll
        for (int q = 0; q < 4; ++q)
          bv[q] = *reinterpret_cast<const bf16x8*>(
              &lds[((half * 4 + q) * 16 + l15) * CT_STR + tk * 64 + slotT]);
        __builtin_amdgcn_s_setprio(1);       // T5: favor MFMA cluster
#pragma unroll
        for (int q = 0; q < 4; ++q) {
          acc[0][half * 4 + q] =
              __builtin_amdgcn_mfma_f32_16x16x32_bf16(avC0, bv[q], acc[0][half * 4 + q], 0, 0, 0);
          acc[1][half * 4 + q] =
              __builtin_amdgcn_mfma_f32_16x16x32_bf16(avC1, bv[q], acc[1][half * 4 + q], 0, 0, 0);
        }
        __builtin_amdgcn_s_setprio(0);
      }
      if (s == 6) {
#pragma unroll
        for (int m = 0; m < 2; ++m) {
          int abase = wn * 32 + m * 16 + l4 * 4;
          float4 p4 = *reinterpret_cast<const float4*>(&phcLc[abase]);
          float4 w4 = *reinterpret_cast<const float4*>(&wbLc[abase]);
#pragma unroll
          for (int n = 0; n < 8; ++n) {
            sn[n] += fast_tanh(acc[m][n][0] + p4.x) * w4.x;
            sn[n] += fast_tanh(acc[m][n][1] + p4.y) * w4.y;
            sn[n] += fast_tanh(acc[m][n][2] + p4.z) * w4.z;
            sn[n] += fast_tanh(acc[m][n][3] + p4.w) * w4.w;
            acc[m][n] = f32x4{0.f, 0.f, 0.f, 0.f};
          }
        }
      }
      avC0 = avN0;
      avC1 = avN1;
    }
#pragma unroll
    for (int m = 0; m < 2; ++m) {
      int abase = 256 + wn * 32 + m * 16 + l4 * 4;
      float4 p4 = *reinterpret_cast<const float4*>(&phcLc[abase]);
      float4 w4 = *reinterpret_cast<const float4*>(&wbLc[abase]);
#pragma unroll
      for (int n = 0; n < 8; ++n) {
        sn[n] += fast_tanh(acc[m][n][0] + p4.x) * w4.x;
        sn[n] += fast_tanh(acc[m][n][1] + p4.y) * w4.y;
        sn[n] += fast_tanh(acc[m][n][2] + p4.z) * w4.z;
        sn[n] += fast_tanh(acc[m][n][3] + p4.w) * w4.w;
      }
    }
#pragma unroll
    for (int n = 0; n < 8; ++n) {
      sn[n] += __shfl_xor(sn[n], 16);
      sn[n] += __shfl_xor(sn[n], 32);
    }
    __syncthreads();
    float* red = reinterpret_cast<float*>(lds);
    if (l4 == 0) {
#pragma unroll
      for (int n = 0; n < 8; ++n) red[wn * 128 + n * 16 + l15] = sn[n];
    }
    __syncthreads();
    if (tid < 128) {
      float r = 0.f;
#pragma unroll
      for (int w = 0; w < 8; ++w) r += red[w * 128 + tid];
      logits_c[(size_t)b * 1024 + h0 + tid] = r;
    }
  }
}

// ------- fused tail: softmax_s + softmax_c + both weighted sums ------------
__launch_bounds__(512)
__global__ void k_weighted(const float* __restrict__ att, const float* __restrict__ logits_s,
                           const float* __restrict__ logits_c, float* __restrict__ out_s,
                           float* __restrict__ out_c, float* __restrict__ out_wsp) {
  __shared__ float wsl[Ll];
  __shared__ float chan[8][Ll];
  __shared__ float wchan[1024];
  __shared__ float4 acmbA[256];
  __shared__ float4 acmbB[256];
  __shared__ float sm[16];
  const int t = threadIdx.x, lane = t & 63, wn = t >> 6;
  const int t2 = t & 255, g = t >> 8;
  const int b = blockIdx.x;

  float xs = (t < Ll) ? logits_s[(size_t)b * Ll + t] : -1e30f;
  float m = xs;
#pragma unroll
  for (int o = 32; o; o >>= 1) m = fmaxf(m, __shfl_xor(m, o));
  if (lane == 0) sm[wn] = m;
  __syncthreads();
  m = fmaxf(fmaxf(fmaxf(sm[0], sm[1]), fmaxf(sm[2], sm[3])),
            fmaxf(fmaxf(sm[4], sm[5]), fmaxf(sm[6], sm[7])));
  float es = (t < Ll) ? __expf(xs - m) : 0.f;
  float ss = es;
#pragma unroll
  for (int o = 32; o; o >>= 1) ss += __shfl_xor(ss, o);
  if (lane == 0) sm[8 + wn] = ss;
  __syncthreads();
  ss = (sm[8] + sm[9]) + (sm[10] + sm[11]) + (sm[12] + sm[13]) + (sm[14] + sm[15]);
  if (t < Ll) {
    float w = es / ss;
    wsl[t] = w;
    out_wsp[(size_t)b * Ll + t] = w;
  }
  __syncthreads();

  float2 xc = *reinterpret_cast<const float2*>(&logits_c[(size_t)b * 1024 + 2 * t]);
  float mc = fmaxf(xc.x, xc.y);
#pragma unroll
  for (int o = 32; o; o >>= 1) mc = fmaxf(mc, __shfl_xor(mc, o));
  if (lane == 0) sm[wn] = mc;
  __syncthreads();
  mc = fmaxf(fmaxf(fmaxf(sm[0], sm[1]), fmaxf(sm[2], sm[3])),
             fmaxf(fmaxf(sm[4], sm[5]), fmaxf(sm[6], sm[7])));
  float e0 = __expf(xc.x - mc), e1 = __expf(xc.y - mc);
  float cs = e0 + e1;
#pragma unroll
  for (int o = 32; o; o >>= 1) cs += __shfl_xor(cs, o);
  if (lane == 0) sm[8 + wn] = cs;
  __syncthreads();
  cs = (sm[8] + sm[9]) + (sm[10] + sm[11]) + (sm[12] + sm[13]) + (sm[14] + sm[15]);
  float rcs = 1.f / cs;
  wchan[2 * t] = e0 * rcs;
  wchan[2 * t + 1] = e1 * rcs;
  __syncthreads();

  float4 wc4 = *reinterpret_cast<const float4*>(&wchan[4 * t2]);
  const float* attb = att + (size_t)b * Ll * 1024;
  float4 accs = {0.f, 0.f, 0.f, 0.f};
  for (int l = g; l < Ll; l += 2) {
    float4 v = *reinterpret_cast<const float4*>(&attb[(size_t)l * 1024 + 4 * t2]);
    float w = wsl[l];
    accs.x += w * v.x; accs.y += w * v.y; accs.z += w * v.z; accs.w += w * v.w;
    float pc = wc4.x * v.x + wc4.y * v.y + wc4.z * v.z + wc4.w * v.w;
#pragma unroll
    for (int o = 32; o; o >>= 1) pc += __shfl_xor(pc, o);
    if (lane == 0) chan[wn][l] = pc;
  }
  (g == 0 ? acmbA : acmbB)[t2] = accs;
  __syncthreads();
  if (t < 256) {
    float4 a = acmbA[t], c = acmbB[t];
    float4 o4 = {a.x + c.x, a.y + c.y, a.z + c.z, a.w + c.w};
    *reinterpret_cast<float4*>(&out_s[(size_t)b * 1024 + 4 * t]) = o4;
  }
  if (t < Ll) {
    int gg = (t & 1) * 4;
    out_c[(size_t)b * Ll + t] =
        (chan[gg][t] + chan[gg + 1][t]) + (chan[gg + 2][t] + chan[gg + 3][t]);
  }
}

// ------------------------------- launcher ----------------------------------
extern "C" void kernel_launch(void* const* d_in, const int* in_sizes, int n_in,
                              void* d_out, int out_size, void* d_ws, size_t ws_size,
                              hipStream_t stream) {
  (void)in_sizes; (void)n_in; (void)out_size; (void)ws_size;
  const float* att     = (const float*)d_in[0];
  const float* h       = (const float*)d_in[1];
  const float* W_att   = (const float*)d_in[2];
  const float* b_att   = (const float*)d_in[3];
  const float* W_h     = (const float*)d_in[4];
  const float* b_h     = (const float*)d_in[5];
  const float* w_alpha = (const float*)d_in[6];
  const float* W_ch    = (const float*)d_in[8];
  const float* b_ch    = (const float*)d_in[9];
  const float* w_beta  = (const float*)d_in[10];
  // d_in[7] b_alpha, d_in[11] b_beta: softmax-shift-invariant, unused

  float* out_ws    = (float*)d_out;                       // [B,H]
  float* out_wc    = out_ws + (size_t)Bb * Hh;            // [B,L]
  float* out_wspat = out_wc + (size_t)Bb * Ll;            // [B,L]

  char* ws = (char*)d_ws;
  float* p_h      = (float*)(ws);                          // 2 MB
  float* logits_s = (float*)(ws + 2097152);                // 802816 B
  float* logits_c = (float*)(ws + 2899968);                // 4 MB
  bf16*  WtP      = (bf16*)(ws + 11288576);                // 1 MB (32 panels)
  bf16*  WctP     = (bf16*)(ws + 12337152);                // 224 KB (7 panels)

  k_prep<<<568, 256, 0, stream>>>(W_att, W_ch, h, W_h, b_h, WtP, WctP, p_h);
  k_dual<<<64 * 177, 512, 0, stream>>>(att, WtP, WctP, b_att, b_ch, p_h,
                                       w_alpha, w_beta, logits_s, logits_c);
  k_weighted<<<1024, 512, 0, stream>>>(att, logits_s, logits_c, out_ws, out_wc, out_wspat);
}

// Round 25
// 782.972 us; speedup vs baseline: 1.1754x; 1.1754x over previous
//
#include <hip/hip_runtime.h>
#include <cstdint>
#include <cstddef>

// ---------------------------------------------------------------------------
// DualAttention: B=1024, L=196, H=1024, A=512
// R25 = R23's k_dual VERBATIM (setprio reverted: it halved achieved
// occupancy and cost +160us — replicates m190's GEMM-setprio regression;
// prio-1 MFMA waves starved the other block type's staging waves) +
// k_prep merge kept (separate kernel, not implicated in the regression).
//  - k_weighted: R15 fused tail verbatim.
// ---------------------------------------------------------------------------

#define DEVI __device__ __forceinline__

typedef __bf16 bf16;
typedef bf16 bf16x4 __attribute__((ext_vector_type(4)));
typedef bf16 bf16x8 __attribute__((ext_vector_type(8)));
typedef float f32x4 __attribute__((ext_vector_type(4)));
typedef unsigned int uint32;

static constexpr int Bb = 1024;
static constexpr int Ll = 196;
static constexpr int Hh = 1024;
static constexpr int BL = Bb * Ll;        // 200704

#define LGKM0     asm volatile("s_waitcnt lgkmcnt(0)" ::: "memory")
#define SBAR()    __builtin_amdgcn_s_barrier()
#define SCHED0()  __builtin_amdgcn_sched_barrier(0)

DEVI float fast_tanh(float x) {
  float e = __expf(2.f * x);
  return 1.f - 2.f * __builtin_amdgcn_rcpf(e + 1.f);
}

DEVI uint32 packbf2(float a, float b) {
  union { bf16 h; unsigned short u; } x, y;
  x.h = (bf16)a; y.h = (bf16)b;
  return (uint32)x.u | ((uint32)y.u << 16);
}

// ---------------- merged prologue: panel builds + p_h ----------------------
// blocks 0..255: build WtP; 256..311: build WctP; 312..567: p_h = h@W_h+b_h.
// Panels: [k0/32][a=0..511][64B]; 16B slot s holds k-octet (s ^ g(a)),
// g(a) = (a>>1)&3.
__global__ void k_prep(const float* __restrict__ W_att, const float* __restrict__ W_ch,
                       const float* __restrict__ h, const float* __restrict__ W_h,
                       const float* __restrict__ b_h, bf16* __restrict__ WtP,
                       bf16* __restrict__ WctP, float* __restrict__ p_h) {
  const int bx = blockIdx.x;
  const int tid = threadIdx.x;
  if (bx < 256) {
    int idx = bx * 256 + tid;                    // 65536
    int a = idx & 511;
    int ko = (idx >> 9) << 3;
    bf16x8 v;
#pragma unroll
    for (int j = 0; j < 8; ++j) v[j] = (bf16)W_att[(size_t)(ko + j) * 512 + a];
    int panel = ko >> 5;
    int slot = ((ko >> 3) & 3) ^ ((a >> 1) & 3);
    *reinterpret_cast<bf16x8*>((char*)WtP + (size_t)panel * 32768 + a * 64 + slot * 16) = v;
  } else if (bx < 312) {
    int idx = (bx - 256) * 256 + tid;            // 14336
    int a = idx & 511;
    int lo = (idx >> 9) << 3;
    bf16x8 v;
#pragma unroll
    for (int j = 0; j < 8; ++j)
      v[j] = (lo + j < Ll) ? (bf16)W_ch[(size_t)(lo + j) * 512 + a] : (bf16)0.f;
    int panel = lo >> 5;
    int slot = ((lo >> 3) & 3) ^ ((a >> 1) & 3);
    *reinterpret_cast<bf16x8*>((char*)WctP + (size_t)panel * 32768 + a * 64 + slot * 16) = v;
  } else {
    int pidx = bx - 312;                         // 0..255
    int a = (pidx & 1) * 256 + tid;
    int b0 = (pidx >> 1) * 8;
    float acc[8] = {0.f, 0.f, 0.f, 0.f, 0.f, 0.f, 0.f, 0.f};
    for (int k = 0; k < 1024; ++k) {
      float w = W_h[(size_t)k * 512 + a];
#pragma unroll
      for (int i = 0; i < 8; ++i) acc[i] += h[(size_t)(b0 + i) * 1024 + k] * w;
    }
#pragma unroll
    for (int i = 0; i < 8; ++i) p_h[(size_t)(b0 + i) * 512 + a] = acc[i] + b_h[a];
  }
}

// ------------- fused GEMM kernel: spatial + channel co-scheduled -----------
// Grid = 64 groups x 177 blocks (49 spatial + 128 channel per group).
#define SP_ASTR 80
#define SP_ST   5120
#define CT_STR 464
#define CH_PHC 59392
#define CH_WB  61440
__launch_bounds__(512)
__global__ void k_dual(const float* __restrict__ att, const bf16* __restrict__ WtP,
                       const bf16* __restrict__ WctP, const float* __restrict__ b_att,
                       const float* __restrict__ b_ch, const float* __restrict__ p_h,
                       const float* __restrict__ w_alpha, const float* __restrict__ w_beta,
                       float* __restrict__ logits_s, float* __restrict__ logits_c) {
  __shared__ alignas(1024) char lds[63488];
  const int tid = threadIdx.x;
  const int lane = tid & 63;
  const int wn = tid >> 6;                  // 0..7
  const int l15 = lane & 15, l4 = lane >> 4;
  const int grpI = blockIdx.x / 177;        // 0..63
  const int rI = blockIdx.x % 177;

  if (rI < 49) {
    // ================== SPATIAL PATH ==================
    const int sb = grpI * 49 + rI;          // 0..3135
    const size_t row0 = (size_t)sb * 64;
    const int slotP = (l4 ^ ((l15 >> 1) & 3)) << 4;
    const int ar = tid >> 3;                // A rows 0..63
    const int aks = (tid & 7) << 2;         // k offset 0,4,...,28
    const char* WtPc = (const char*)WtP;
    const float* apbase = att + (row0 + ar) * 1024 + aks;
    const int awoff = ar * SP_ASTR + (aks << 1);
    int boff[4];
#pragma unroll
    for (int n = 0; n < 4; ++n) boff[n] = (wn * 64 + n * 16 + l15) * 64 + slotP;

    f32x4 acc[4][4];
#pragma unroll
    for (int m = 0; m < 4; ++m)
#pragma unroll
      for (int n = 0; n < 4; ++n) acc[m][n] = f32x4{0.f, 0.f, 0.f, 0.f};

    bf16x8 bvC0 = *reinterpret_cast<const bf16x8*>(WtPc + boff[0]);
    bf16x8 bvC1 = *reinterpret_cast<const bf16x8*>(WtPc + boff[1]);
    bf16x8 bvC2 = *reinterpret_cast<const bf16x8*>(WtPc + boff[2]);
    bf16x8 bvC3 = *reinterpret_cast<const bf16x8*>(WtPc + boff[3]);

#pragma unroll 1
    for (int ph = 0; ph < 4; ++ph) {
      {
        float4 c[8];
#pragma unroll
        for (int st = 0; st < 8; ++st)
          c[st] = *reinterpret_cast<const float4*>(apbase + ph * 256 + st * 32);
#pragma unroll
        for (int st = 0; st < 8; ++st) {
          bf16x4 w0 = {(bf16)c[st].x, (bf16)c[st].y, (bf16)c[st].z, (bf16)c[st].w};
          *reinterpret_cast<bf16x4*>(&lds[st * SP_ST + awoff]) = w0;
        }
      }
      LGKM0;
      SCHED0();
      SBAR();
      SCHED0();
#pragma unroll 1
      for (int st = 0; st < 8; ++st) {
        const int t = ph * 8 + st;
        bf16x8 bvN0 = bvC0, bvN1 = bvC1, bvN2 = bvC2, bvN3 = bvC3;
        if (t < 31) {
          const char* bpan = WtPc + (size_t)(t + 1) * 32768;
          bvN0 = *reinterpret_cast<const bf16x8*>(bpan + boff[0]);
          bvN1 = *reinterpret_cast<const bf16x8*>(bpan + boff[1]);
          bvN2 = *reinterpret_cast<const bf16x8*>(bpan + boff[2]);
          bvN3 = *reinterpret_cast<const bf16x8*>(bpan + boff[3]);
        }
        bf16x8 af[4];
#pragma unroll
        for (int m = 0; m < 4; ++m)
          af[m] = *reinterpret_cast<const bf16x8*>(
              &lds[st * SP_ST + (m * 16 + l15) * SP_ASTR + (l4 << 4)]);
#pragma unroll
        for (int m = 0; m < 4; ++m) {
          acc[m][0] = __builtin_amdgcn_mfma_f32_16x16x32_bf16(af[m], bvC0, acc[m][0], 0, 0, 0);
          acc[m][1] = __builtin_amdgcn_mfma_f32_16x16x32_bf16(af[m], bvC1, acc[m][1], 0, 0, 0);
          acc[m][2] = __builtin_amdgcn_mfma_f32_16x16x32_bf16(af[m], bvC2, acc[m][2], 0, 0, 0);
          acc[m][3] = __builtin_amdgcn_mfma_f32_16x16x32_bf16(af[m], bvC3, acc[m][3], 0, 0, 0);
        }
        bvC0 = bvN0; bvC1 = bvN1; bvC2 = bvN2; bvC3 = bvN3;
      }
      LGKM0;
      SCHED0();
      SBAR();
      SCHED0();
    }

    // epilogue
    float wa[4], ba[4], ph0[4], ph1[4];
    unsigned b0i = (unsigned)row0 / 196u;
    unsigned b1i = (unsigned)(row0 + 63) / 196u;
    unsigned bnd = (b0i + 1) * 196u;
#pragma unroll
    for (int n = 0; n < 4; ++n) {
      int a = wn * 64 + n * 16 + l15;
      wa[n] = w_alpha[a];
      ba[n] = b_att[a];
      ph0[n] = p_h[(size_t)b0i * 512 + a];
      ph1[n] = p_h[(size_t)b1i * 512 + a];
    }
    float* red = reinterpret_cast<float*>(lds);
#pragma unroll
    for (int m = 0; m < 4; ++m) {
#pragma unroll
      for (int j = 0; j < 4; ++j) {
        int rloc = m * 16 + l4 * 4 + j;
        unsigned R = (unsigned)row0 + rloc;
        bool hib = R >= bnd;
        float s = 0.f;
#pragma unroll
        for (int n = 0; n < 4; ++n)
          s += fast_tanh(acc[m][n][j] + ba[n] + (hib ? ph1[n] : ph0[n])) * wa[n];
        s += __shfl_xor(s, 1);
        s += __shfl_xor(s, 2);
        s += __shfl_xor(s, 4);
        s += __shfl_xor(s, 8);
        if (l15 == 0) red[wn * 64 + rloc] = s;
      }
    }
    __syncthreads();
    if (tid < 64) {
      float r = 0.f;
#pragma unroll
      for (int w = 0; w < 8; ++w) r += red[w * 64 + tid];
      logits_s[row0 + tid] = r;
    }
  } else {
    // ================== CHANNEL PATH ==================
    const int cidx = grpI * 128 + (rI - 49);  // 0..8191
    const int b = cidx >> 3;
    const int h0 = (cidx & 7) * 128;
    const float* attb = att + (size_t)b * Ll * 1024 + h0;
    const char* Pc = (const char*)WctP;
    const int slotP = (l4 ^ ((l15 >> 1) & 3)) << 4;
    const int slotT = (l4 ^ ((l15 >> 2) & 3)) << 4;
    int poff0 = (wn * 32 + l15) * 64 + slotP;
    int poff1 = (wn * 32 + 16 + l15) * 64 + slotP;

    float pr = p_h[(size_t)b * 512 + tid];
    float bc = b_ch[tid];
    float wb = w_beta[tid];
    bf16x8 avC0 = *reinterpret_cast<const bf16x8*>(Pc + poff0);
    bf16x8 avC1 = *reinterpret_cast<const bf16x8*>(Pc + poff1);
    {
      const int grp = tid >> 8;
      const int t2 = tid & 255;
      const int lp = t2 >> 4;
      const int hq = (t2 & 15) << 2;
      const int usw = lp ^ ((t2 & 3) << 2);
      const int ch0 = grp ? 4 : 0;
      const int nch = grp ? 3 : 4;
#pragma unroll
      for (int hh = 0; hh < 2; ++hh) {
        const int hb = hq + 64 * hh;
        float4 va[4], vb[4];
#pragma unroll
        for (int i = 0; i < 4; ++i) {
          if (i >= nch) break;
          int ch = ch0 + i;
          int lg = ch * 32 + 2 * lp;
          va[i] = float4{0.f, 0.f, 0.f, 0.f};
          vb[i] = float4{0.f, 0.f, 0.f, 0.f};
          if (lg < Ll)
            va[i] = *reinterpret_cast<const float4*>(&attb[(size_t)lg * 1024 + hb]);
          if (lg + 1 < Ll)
            vb[i] = *reinterpret_cast<const float4*>(&attb[(size_t)(lg + 1) * 1024 + hb]);
        }
#pragma unroll
        for (int i = 0; i < 4; ++i) {
          if (i >= nch) break;
          int ch = ch0 + i;
          uint32 pk[4] = {packbf2(va[i].x, vb[i].x), packbf2(va[i].y, vb[i].y),
                          packbf2(va[i].z, vb[i].z), packbf2(va[i].w, vb[i].w)};
#pragma unroll
          for (int c = 0; c < 4; ++c)
            *reinterpret_cast<uint32*>(
                &lds[(hb + c) * CT_STR + ch * 64 + 4 * usw]) = pk[c];
        }
      }
    }
    {
      float* phcL = reinterpret_cast<float*>(&lds[CH_PHC]);
      float* wbL = reinterpret_cast<float*>(&lds[CH_WB]);
      phcL[tid] = pr + bc;
      wbL[tid] = wb;
    }

    f32x4 acc[2][8];
#pragma unroll
    for (int m = 0; m < 2; ++m)
#pragma unroll
      for (int n = 0; n < 8; ++n) acc[m][n] = f32x4{0.f, 0.f, 0.f, 0.f};
    float sn[8] = {0.f, 0.f, 0.f, 0.f, 0.f, 0.f, 0.f, 0.f};
    const float* phcLc = reinterpret_cast<const float*>(&lds[CH_PHC]);
    const float* wbLc = reinterpret_cast<const float*>(&lds[CH_WB]);

    LGKM0;
    SCHED0();
    SBAR();
    SCHED0();

#pragma unroll 1
    for (int s = 0; s < 14; ++s) {
      const int tk = (s >= 7) ? s - 7 : s;
      bf16x8 avN0 = avC0, avN1 = avC1;
      if (s < 13) {
        const int s1 = s + 1;
        const char* pan = Pc + (size_t)((s1 >= 7) ? s1 - 7 : s1) * 32768 +
                          ((s1 >= 7) ? 16384 : 0);
        avN0 = *reinterpret_cast<const bf16x8*>(pan + poff0);
        avN1 = *reinterpret_cast<const bf16x8*>(pan + poff1);
      }
#pragma unroll
      for (int half = 0; half < 2; ++half) {
        bf16x8 bv[4];
#pragma unroll
        for (int q = 0; q < 4; ++q)
          bv[q] = *reinterpret_cast<const bf16x8*>(
              &lds[((half * 4 + q) * 16 + l15) * CT_STR + tk * 64 + slotT]);
#pragma unroll
        for (int q = 0; q < 4; ++q) {
          acc[0][half * 4 + q] =
              __builtin_amdgcn_mfma_f32_16x16x32_bf16(avC0, bv[q], acc[0][half * 4 + q], 0, 0, 0);
          acc[1][half * 4 + q] =
              __builtin_amdgcn_mfma_f32_16x16x32_bf16(avC1, bv[q], acc[1][half * 4 + q], 0, 0, 0);
        }
      }
      if (s == 6) {
#pragma unroll
        for (int m = 0; m < 2; ++m) {
          int abase = wn * 32 + m * 16 + l4 * 4;
          float4 p4 = *reinterpret_cast<const float4*>(&phcLc[abase]);
          float4 w4 = *reinterpret_cast<const float4*>(&wbLc[abase]);
#pragma unroll
          for (int n = 0; n < 8; ++n) {
            sn[n] += fast_tanh(acc[m][n][0] + p4.x) * w4.x;
            sn[n] += fast_tanh(acc[m][n][1] + p4.y) * w4.y;
            sn[n] += fast_tanh(acc[m][n][2] + p4.z) * w4.z;
            sn[n] += fast_tanh(acc[m][n][3] + p4.w) * w4.w;
            acc[m][n] = f32x4{0.f, 0.f, 0.f, 0.f};
          }
        }
      }
      avC0 = avN0;
      avC1 = avN1;
    }
#pragma unroll
    for (int m = 0; m < 2; ++m) {
      int abase = 256 + wn * 32 + m * 16 + l4 * 4;
      float4 p4 = *reinterpret_cast<const float4*>(&phcLc[abase]);
      float4 w4 = *reinterpret_cast<const float4*>(&wbLc[abase]);
#pragma unroll
      for (int n = 0; n < 8; ++n) {
        sn[n] += fast_tanh(acc[m][n][0] + p4.x) * w4.x;
        sn[n] += fast_tanh(acc[m][n][1] + p4.y) * w4.y;
        sn[n] += fast_tanh(acc[m][n][2] + p4.z) * w4.z;
        sn[n] += fast_tanh(acc[m][n][3] + p4.w) * w4.w;
      }
    }
#pragma unroll
    for (int n = 0; n < 8; ++n) {
      sn[n] += __shfl_xor(sn[n], 16);
      sn[n] += __shfl_xor(sn[n], 32);
    }
    __syncthreads();
    float* red = reinterpret_cast<float*>(lds);
    if (l4 == 0) {
#pragma unroll
      for (int n = 0; n < 8; ++n) red[wn * 128 + n * 16 + l15] = sn[n];
    }
    __syncthreads();
    if (tid < 128) {
      float r = 0.f;
#pragma unroll
      for (int w = 0; w < 8; ++w) r += red[w * 128 + tid];
      logits_c[(size_t)b * 1024 + h0 + tid] = r;
    }
  }
}

// ------- fused tail: softmax_s + softmax_c + both weighted sums ------------
__launch_bounds__(512)
__global__ void k_weighted(const float* __restrict__ att, const float* __restrict__ logits_s,
                           const float* __restrict__ logits_c, float* __restrict__ out_s,
                           float* __restrict__ out_c, float* __restrict__ out_wsp) {
  __shared__ float wsl[Ll];
  __shared__ float chan[8][Ll];
  __shared__ float wchan[1024];
  __shared__ float4 acmbA[256];
  __shared__ float4 acmbB[256];
  __shared__ float sm[16];
  const int t = threadIdx.x, lane = t & 63, wn = t >> 6;
  const int t2 = t & 255, g = t >> 8;
  const int b = blockIdx.x;

  float xs = (t < Ll) ? logits_s[(size_t)b * Ll + t] : -1e30f;
  float m = xs;
#pragma unroll
  for (int o = 32; o; o >>= 1) m = fmaxf(m, __shfl_xor(m, o));
  if (lane == 0) sm[wn] = m;
  __syncthreads();
  m = fmaxf(fmaxf(fmaxf(sm[0], sm[1]), fmaxf(sm[2], sm[3])),
            fmaxf(fmaxf(sm[4], sm[5]), fmaxf(sm[6], sm[7])));
  float es = (t < Ll) ? __expf(xs - m) : 0.f;
  float ss = es;
#pragma unroll
  for (int o = 32; o; o >>= 1) ss += __shfl_xor(ss, o);
  if (lane == 0) sm[8 + wn] = ss;
  __syncthreads();
  ss = (sm[8] + sm[9]) + (sm[10] + sm[11]) + (sm[12] + sm[13]) + (sm[14] + sm[15]);
  if (t < Ll) {
    float w = es / ss;
    wsl[t] = w;
    out_wsp[(size_t)b * Ll + t] = w;
  }
  __syncthreads();

  float2 xc = *reinterpret_cast<const float2*>(&logits_c[(size_t)b * 1024 + 2 * t]);
  float mc = fmaxf(xc.x, xc.y);
#pragma unroll
  for (int o = 32; o; o >>= 1) mc = fmaxf(mc, __shfl_xor(mc, o));
  if (lane == 0) sm[wn] = mc;
  __syncthreads();
  mc = fmaxf(fmaxf(fmaxf(sm[0], sm[1]), fmaxf(sm[2], sm[3])),
             fmaxf(fmaxf(sm[4], sm[5]), fmaxf(sm[6], sm[7])));
  float e0 = __expf(xc.x - mc), e1 = __expf(xc.y - mc);
  float cs = e0 + e1;
#pragma unroll
  for (int o = 32; o; o >>= 1) cs += __shfl_xor(cs, o);
  if (lane == 0) sm[8 + wn] = cs;
  __syncthreads();
  cs = (sm[8] + sm[9]) + (sm[10] + sm[11]) + (sm[12] + sm[13]) + (sm[14] + sm[15]);
  float rcs = 1.f / cs;
  wchan[2 * t] = e0 * rcs;
  wchan[2 * t + 1] = e1 * rcs;
  __syncthreads();

  float4 wc4 = *reinterpret_cast<const float4*>(&wchan[4 * t2]);
  const float* attb = att + (size_t)b * Ll * 1024;
  float4 accs = {0.f, 0.f, 0.f, 0.f};
  for (int l = g; l < Ll; l += 2) {
    float4 v = *reinterpret_cast<const float4*>(&attb[(size_t)l * 1024 + 4 * t2]);
    float w = wsl[l];
    accs.x += w * v.x; accs.y += w * v.y; accs.z += w * v.z; accs.w += w * v.w;
    float pc = wc4.x * v.x + wc4.y * v.y + wc4.z * v.z + wc4.w * v.w;
#pragma unroll
    for (int o = 32; o; o >>= 1) pc += __shfl_xor(pc, o);
    if (lane == 0) chan[wn][l] = pc;
  }
  (g == 0 ? acmbA : acmbB)[t2] = accs;
  __syncthreads();
  if (t < 256) {
    float4 a = acmbA[t], c = acmbB[t];
    float4 o4 = {a.x + c.x, a.y + c.y, a.z + c.z, a.w + c.w};
    *reinterpret_cast<float4*>(&out_s[(size_t)b * 1024 + 4 * t]) = o4;
  }
  if (t < Ll) {
    int gg = (t & 1) * 4;
    out_c[(size_t)b * Ll + t] =
        (chan[gg][t] + chan[gg + 1][t]) + (chan[gg + 2][t] + chan[gg + 3][t]);
  }
}

// ------------------------------- launcher ----------------------------------
extern "C" void kernel_launch(void* const* d_in, const int* in_sizes, int n_in,
                              void* d_out, int out_size, void* d_ws, size_t ws_size,
                              hipStream_t stream) {
  (void)in_sizes; (void)n_in; (void)out_size; (void)ws_size;
  const float* att     = (const float*)d_in[0];
  const float* h       = (const float*)d_in[1];
  const float* W_att   = (const float*)d_in[2];
  const float* b_att   = (const float*)d_in[3];
  const float* W_h     = (const float*)d_in[4];
  const float* b_h     = (const float*)d_in[5];
  const float* w_alpha = (const float*)d_in[6];
  const float* W_ch    = (const float*)d_in[8];
  const float* b_ch    = (const float*)d_in[9];
  const float* w_beta  = (const float*)d_in[10];
  // d_in[7] b_alpha, d_in[11] b_beta: softmax-shift-invariant, unused

  float* out_ws    = (float*)d_out;                       // [B,H]
  float* out_wc    = out_ws + (size_t)Bb * Hh;            // [B,L]
  float* out_wspat = out_wc + (size_t)Bb * Ll;            // [B,L]

  char* ws = (char*)d_ws;
  float* p_h      = (float*)(ws);                          // 2 MB
  float* logits_s = (float*)(ws + 2097152);                // 802816 B
  float* logits_c = (float*)(ws + 2899968);                // 4 MB
  bf16*  WtP      = (bf16*)(ws + 11288576);                // 1 MB (32 panels)
  bf16*  WctP     = (bf16*)(ws + 12337152);                // 224 KB (7 panels)

  k_prep<<<568, 256, 0, stream>>>(W_att, W_ch, h, W_h, b_h, WtP, WctP, p_h);
  k_dual<<<64 * 177, 512, 0, stream>>>(att, WtP, WctP, b_att, b_ch, p_h,
                                       w_alpha, w_beta, logits_s, logits_c);
  k_weighted<<<1024, 512, 0, stream>>>(att, logits_s, logits_c, out_ws, out_wc, out_wspat);
}